// Round 1
// baseline (282.659 us; speedup 1.0000x reference)
//
#include <hip/hip_runtime.h>

// z[b,d] = x[b,d] * (1 + sum_{i=1..K} w[i-1,d] * x[b,(d+i) mod D])
// B=8192, D=4096, K=16, fp32. Memory-bound: ideal ~268 MB HBM traffic.

#define D 4096
#define K 16
#define TPB 256
#define ROWS 16

__global__ __launch_bounds__(TPB) void quad_enhancer_kernel(
    const float* __restrict__ x, const float* __restrict__ w,
    float* __restrict__ out, int B) {
  // dq: this thread's float4 column-group index in [0, D/4)
  const int dq = blockIdx.x * TPB + threadIdx.x;
  const int b0 = blockIdx.y * ROWS;

  // Load w[:, 4*dq .. 4*dq+3] once into registers; reused across ROWS rows.
  float4 wv[K];
#pragma unroll
  for (int i = 0; i < K; ++i) {
    wv[i] = ((const float4*)(w + i * D))[dq];
  }

#pragma unroll 1
  for (int r = 0; r < ROWS; ++r) {
    const int b = b0 + r;
    if (b >= B) break;
    const float4* xrow = (const float4*)(x + (size_t)b * D);

    // Need x[b, d0 .. d0+19] (mod D). D multiple of 4 => aligned float4
    // groups never straddle the wrap: group (dq+j) & (D/4-1) is contiguous.
    float xs[20];
#pragma unroll
    for (int j = 0; j < 5; ++j) {
      float4 v = xrow[(dq + j) & (D / 4 - 1)];
      xs[4 * j + 0] = v.x;
      xs[4 * j + 1] = v.y;
      xs[4 * j + 2] = v.z;
      xs[4 * j + 3] = v.w;
    }

    float ax = 1.0f, ay = 1.0f, az = 1.0f, aw = 1.0f;
#pragma unroll
    for (int i = 0; i < K; ++i) {
      // shift = i+1; element k uses xs[k + i + 1]
      ax = fmaf(wv[i].x, xs[0 + i + 1], ax);
      ay = fmaf(wv[i].y, xs[1 + i + 1], ay);
      az = fmaf(wv[i].z, xs[2 + i + 1], az);
      aw = fmaf(wv[i].w, xs[3 + i + 1], aw);
    }

    float4 o;
    o.x = xs[0] * ax;
    o.y = xs[1] * ay;
    o.z = xs[2] * az;
    o.w = xs[3] * aw;
    ((float4*)(out + (size_t)b * D))[dq] = o;
  }
}

extern "C" void kernel_launch(void* const* d_in, const int* in_sizes, int n_in,
                              void* d_out, int out_size, void* d_ws, size_t ws_size,
                              hipStream_t stream) {
  const float* x = (const float*)d_in[0];
  const float* w = (const float*)d_in[1];
  float* out = (float*)d_out;
  const int B = in_sizes[0] / D;  // 8192

  dim3 grid(D / 4 / TPB, (B + ROWS - 1) / ROWS);  // (4, 512)
  quad_enhancer_kernel<<<grid, TPB, 0, stream>>>(x, w, out, B);
}